// Round 1
// baseline (355.192 us; speedup 1.0000x reference)
//
#include <hip/hip_runtime.h>

// ---------------- problem constants ----------------
#define NFFT    2048
#define HOPSZ   512
#define BATCH   8
#define TFRAMES 2048
#define FBINS   1025
#define OUTLEN  1048064           // HOP*(T-1)
#define TOTALP  1050112           // NFFT + HOP*(T-1)
#define KPAD    2080              // 2050 padded to mult of 32
#define MROWS   16384             // BATCH*TFRAMES

typedef float  f32x4  __attribute__((ext_vector_type(4)));
typedef __bf16 bf16x8 __attribute__((ext_vector_type(8)));

__device__ __forceinline__ unsigned short f2bf(float f) {
    unsigned u = __float_as_uint(f);
    u += 0x7fffu + ((u >> 16) & 1u);       // round-to-nearest-even
    return (unsigned short)(u >> 16);
}

// ---------------- Wt[a][k] table: bf16, K-contiguous (pre-transposed) -------
// W[k,a]: k<1025  ->  c_k * cos(2*pi*k*a/N)/N * win[a]
//         k<2050  -> -c_b * sin(2*pi*b*a/N)/N * win[a],  b=k-1025
//         else 0 (K padding)
__global__ void build_w(unsigned short* __restrict__ Wt) {
    int k = blockIdx.x * 256 + threadIdx.x;
    int a = blockIdx.y;
    if (k >= KPAD) return;
    float win   = 0.5f - 0.5f * cospif((float)a * (1.0f / 1024.0f));
    float scale = win * (1.0f / 2048.0f);
    float v = 0.0f;
    if (k < 1025) {
        int   m = (k * a) & 2047;                 // exact angle reduction
        float c = (k == 0 || k == 1024) ? 1.0f : 2.0f;
        v = c * cospif((float)m * (1.0f / 1024.0f)) * scale;
    } else if (k < 2050) {
        int   bb = k - 1025;
        int   m  = (bb * a) & 2047;
        float c  = (bb == 0 || bb == 1024) ? 1.0f : 2.0f;
        v = -c * sinpif((float)m * (1.0f / 1024.0f)) * scale;
    }
    Wt[(size_t)a * KPAD + k] = f2bf(v);
}

// ---------------- X[bt][k] = [real | imag | 0-pad] in bf16 ------------------
__global__ void conv_x(const float* __restrict__ re, const float* __restrict__ im,
                       unsigned short* __restrict__ X) {
    int k  = blockIdx.x * 256 + threadIdx.x;
    int bt = blockIdx.y;
    if (k >= KPAD) return;
    float v = 0.0f;
    if (k < 1025)      v = re[(size_t)bt * FBINS + k];
    else if (k < 2050) v = im[(size_t)bt * FBINS + (k - 1025)];
    X[(size_t)bt * KPAD + k] = f2bf(v);
}

// ---------------- 1 / window_sumsquare --------------------------------------
__global__ void build_invws(float* __restrict__ iw) {
    int p = blockIdx.x * 256 + threadIdx.x;
    if (p >= TOTALP) return;
    int tmax = p >> 9;            if (tmax > TFRAMES - 1) tmax = TFRAMES - 1;
    int tmin = (p - 1536) >> 9;   if (tmin < 0) tmin = 0;   // ceil((p-2047)/512)
    float s = 0.0f;
    for (int t = tmin; t <= tmax; ++t) {
        int   a = p - (t << 9);
        float w = 0.5f - 0.5f * cospif((float)a * (1.0f / 1024.0f));
        s += w * w;
    }
    s = fmaxf(s, 1e-8f);
    iw[p] = 1.0f / s;
}

// ---------------- GEMM (bf16 MFMA) + fused overlap-add ----------------------
// C[bt, a] tiles of 128x128; 4 waves in 2x2; each wave 64x64 = 4x4 frags of 16x16.
#define BM  128
#define BN  128
#define LDT 40     // padded LDS row stride (bf16 elems): 80B -> conflict-free-ish

__global__ __launch_bounds__(256) void gemm_ola(
    const unsigned short* __restrict__ X,   // [MROWS][KPAD]
    const unsigned short* __restrict__ Wt,  // [NFFT][KPAD]
    const float*          __restrict__ iw,  // [TOTALP]
    float*                __restrict__ out) // [BATCH][OUTLEN]
{
    __shared__ __align__(16) unsigned short As[BM * LDT];
    __shared__ __align__(16) unsigned short Bs[BN * LDT];

    const int tid  = threadIdx.x;
    const int lane = tid & 63;
    const int w    = tid >> 6;
    const int wr   = w >> 1, wc = w & 1;
    const int l16  = lane & 15, lhi = lane >> 4;

    const int rowBase = blockIdx.x * BM;    // bt
    const int colBase = blockIdx.y * BN;    // a

    // staging: 512 chunks of 8 bf16 per tile; 256 threads x 2 chunks
    const int r0 = tid >> 2,          q0 = (tid & 3) * 8;
    const int r1 = (tid + 256) >> 2,  q1 = ((tid + 256) & 3) * 8;

    const size_t xrow0 = (size_t)(rowBase + r0) * KPAD;
    const size_t xrow1 = (size_t)(rowBase + r1) * KPAD;
    const size_t wrow0 = (size_t)(colBase + r0) * KPAD;
    const size_t wrow1 = (size_t)(colBase + r1) * KPAD;

    f32x4 acc[4][4];
    #pragma unroll
    for (int i = 0; i < 4; ++i)
        #pragma unroll
        for (int j = 0; j < 4; ++j)
            acc[i][j] = f32x4{0.f, 0.f, 0.f, 0.f};

    for (int ks = 0; ks < KPAD / 32; ++ks) {
        const int k0 = ks * 32;
        uint4 a0 = *(const uint4*)(X  + xrow0 + k0 + q0);
        uint4 a1 = *(const uint4*)(X  + xrow1 + k0 + q1);
        uint4 b0 = *(const uint4*)(Wt + wrow0 + k0 + q0);
        uint4 b1 = *(const uint4*)(Wt + wrow1 + k0 + q1);
        __syncthreads();                       // previous iter's reads done
        *(uint4*)(As + r0 * LDT + q0) = a0;
        *(uint4*)(As + r1 * LDT + q1) = a1;
        *(uint4*)(Bs + r0 * LDT + q0) = b0;
        *(uint4*)(Bs + r1 * LDT + q1) = b1;
        __syncthreads();

        bf16x8 af[4], bfr[4];
        #pragma unroll
        for (int mi = 0; mi < 4; ++mi)
            af[mi] = *(const bf16x8*)(As + (wr * 64 + mi * 16 + l16) * LDT + lhi * 8);
        #pragma unroll
        for (int ni = 0; ni < 4; ++ni)
            bfr[ni] = *(const bf16x8*)(Bs + (wc * 64 + ni * 16 + l16) * LDT + lhi * 8);
        #pragma unroll
        for (int mi = 0; mi < 4; ++mi)
            #pragma unroll
            for (int ni = 0; ni < 4; ++ni)
                acc[mi][ni] = __builtin_amdgcn_mfma_f32_16x16x32_bf16(
                    af[mi], bfr[ni], acc[mi][ni], 0, 0, 0);
    }

    // fused overlap-add: frame t, intra-frame offset a -> sample p = t*512 + a
    #pragma unroll
    for (int mi = 0; mi < 4; ++mi) {
        const int grBase = rowBase + wr * 64 + mi * 16 + lhi * 4;
        #pragma unroll
        for (int ni = 0; ni < 4; ++ni) {
            const int gc = colBase + wc * 64 + ni * 16 + l16;
            #pragma unroll
            for (int r = 0; r < 4; ++r) {
                const int row = grBase + r;          // bt
                const int t   = row & (TFRAMES - 1);
                const int b   = row >> 11;
                const int p   = t * HOPSZ + gc;
                const int n   = p - (NFFT / 2);      // center=True slice
                if (n >= 0 && n < OUTLEN)
                    unsafeAtomicAdd(out + (size_t)b * OUTLEN + n,
                                    acc[mi][ni][r] * iw[p]);
            }
        }
    }
}

// ---------------- launch -----------------------------------------------------
extern "C" void kernel_launch(void* const* d_in, const int* in_sizes, int n_in,
                              void* d_out, int out_size, void* d_ws, size_t ws_size,
                              hipStream_t stream) {
    const float* re = (const float*)d_in[0];
    const float* im = (const float*)d_in[1];
    float* out = (float*)d_out;

    char* ws = (char*)d_ws;
    unsigned short* X    = (unsigned short*)(ws);                        // 16384*2080*2 = 68,157,440 B
    unsigned short* Wt   = (unsigned short*)(ws + 68157440);             //  2048*2080*2 =  8,519,680 B
    float*          invw = (float*)        (ws + 68157440 + 8519680);   //  1050112*4   =  4,200,448 B

    hipMemsetAsync(d_out, 0, (size_t)out_size * sizeof(float), stream);

    build_w    <<<dim3(9, NFFT),    256, 0, stream>>>(Wt);
    conv_x     <<<dim3(9, MROWS),   256, 0, stream>>>(re, im, X);
    build_invws<<<dim3(4102),       256, 0, stream>>>(invw);
    gemm_ola   <<<dim3(MROWS / BM, NFFT / BN), 256, 0, stream>>>(X, Wt, invw, out);
}